// Round 1
// baseline (106.933 us; speedup 1.0000x reference)
//
#include <hip/hip_runtime.h>

// Problem: N=32, C=96, H=W=56. HW=3136, NP = N*HW = 100352.
// d_out = [ out (9,633,792 f32) | fmap (9,633,792 f32) ]
//
// ws layout (float index):
//   [    0,  9216) w1t[(g*96+ci)*48 + o]  = w1[(g*48+o)*96 + ci]
//   [ 9216, 12288) w2t[c*32 + o]          = w2[((c>>5)*32+o)*32 + (c&31)]
//   [12288, 12480) s1[192]   bn1 scale
//   [12480, 12672) b1[192]   bn1 bias
//   [12672, 12768) s2[96]
//   [12768, 12864) b2[96]
//   [12864, 12960) wy[96]    frac(dy)
//   [12960, 13056) wx[96]    frac(dx)
//   [13056, 13152) ay[96]    (int) floor(dy)
//   [13152, 13248) ax[96]    (int) floor(dx)

#define WS_W1T 0
#define WS_W2T 9216
#define WS_S1  12288
#define WS_B1  12480
#define WS_S2  12672
#define WS_B2  12768
#define WS_WY  12864
#define WS_WX  12960
#define WS_AY  13056
#define WS_AX  13152

#define HW   3136
#define CC   96
#define NB   32

__global__ __launch_bounds__(256) void precompute_k(
    const float* __restrict__ g1, const float* __restrict__ be1,
    const float* __restrict__ m1, const float* __restrict__ v1,
    const float* __restrict__ g2, const float* __restrict__ be2,
    const float* __restrict__ m2, const float* __restrict__ v2,
    const float* __restrict__ w1, const float* __restrict__ w2,
    const float* __restrict__ shift, float* __restrict__ ws) {
  const int tid = threadIdx.x;
  for (int i = tid; i < 9216; i += 256) {
    int gci = i / 48, o = i - gci * 48;
    int g = gci / 96, ci = gci - g * 96;
    ws[WS_W1T + i] = w1[(g * 48 + o) * 96 + ci];
  }
  for (int i = tid; i < 3072; i += 256) {
    int c = i >> 5, o = i & 31;
    int g = c >> 5, ci = c & 31;
    ws[WS_W2T + i] = w2[(g * 32 + o) * 32 + ci];
  }
  for (int i = tid; i < 192; i += 256) {
    float s = g1[i] / sqrtf(v1[i] + 1e-5f);
    ws[WS_S1 + i] = s;
    ws[WS_B1 + i] = be1[i] - m1[i] * s;
  }
  if (tid < 96) {
    int i = tid;
    float s = g2[i] / sqrtf(v2[i] + 1e-5f);
    ws[WS_S2 + i] = s;
    ws[WS_B2 + i] = be2[i] - m2[i] * s;
    float dy = shift[2 * i], dx = shift[2 * i + 1];
    float fy = floorf(dy), fx = floorf(dx);
    ws[WS_WY + i] = dy - fy;
    ws[WS_WX + i] = dx - fx;
    ((int*)ws)[WS_AY + i] = (int)fy;
    ((int*)ws)[WS_AX + i] = (int)fx;
  }
}

// K1: fmap = conv1x1_g2( bnrelu1( concat(x0, f1, x1, f0) ), w1 )
// Wave = 64 consecutive pixels x one group (48 out channels).
// Block = 256 threads = 4 waves = 128 pixels x 2 groups. grid = NP/128 = 784.
// Concat mapping: g=0: ci<48 -> x[ci], ci>=48 -> prev[ci]
//                 g=1: ci<48 -> x[48+ci], ci>=48 -> prev[ci-48]
__global__ __launch_bounds__(256) void k1_conv1(
    const float* __restrict__ x, const float* __restrict__ prev,
    const float* __restrict__ ws, float* __restrict__ fmap) {
  const int lane = threadIdx.x & 63;
  const int wave = threadIdx.x >> 6;
  const int g = __builtin_amdgcn_readfirstlane(wave & 1);
  const int P = blockIdx.x * 128 + (wave >> 1) * 64 + lane;
  const int n = P / HW;
  const int p = P - n * HW;

  const float* s1 = ws + WS_S1 + g * 96;
  const float* b1 = ws + WS_B1 + g * 96;
  const float* wt = ws + WS_W1T + g * 96 * 48;

  float acc[48];
#pragma unroll
  for (int o = 0; o < 48; ++o) acc[o] = 0.f;

  const int nb = n * CC * HW + p;
  const float* srcA = (g == 0) ? (x + nb) : (x + nb + 48 * HW);
  const float* srcB = (g == 0) ? (prev + nb + 48 * HW) : (prev + nb);

  for (int ci = 0; ci < 48; ++ci) {
    float v = srcA[ci * HW];
    v = fmaxf(fmaf(v, s1[ci], b1[ci]), 0.f);
    const float* wr = wt + ci * 48;
#pragma unroll
    for (int o = 0; o < 48; ++o) acc[o] = fmaf(wr[o], v, acc[o]);
  }
  for (int ci = 0; ci < 48; ++ci) {
    float v = srcB[ci * HW];
    v = fmaxf(fmaf(v, s1[48 + ci], b1[48 + ci]), 0.f);
    const float* wr = wt + (48 + ci) * 48;
#pragma unroll
    for (int o = 0; o < 48; ++o) acc[o] = fmaf(wr[o], v, acc[o]);
  }

  float* ob = fmap + nb + (g * 48) * HW;
#pragma unroll
  for (int o = 0; o < 48; ++o) ob[o * HW] = acc[o];
}

// K2: out = conv1x1_g3( active_shift( bnrelu2(fmap) ), w2 ) + x
// Wave = 64 consecutive pixels x one group (32 out ch). Block = 192 = 3 waves
// (3 groups, same 64 pixels). grid = NP/64 = 1568.
__global__ __launch_bounds__(192) void k2_shift_conv2(
    const float* __restrict__ x, const float* __restrict__ fmap,
    const float* __restrict__ ws, float* __restrict__ out) {
  const int lane = threadIdx.x & 63;
  const int g = __builtin_amdgcn_readfirstlane(threadIdx.x >> 6);  // 0..2
  const int P = blockIdx.x * 64 + lane;
  const int n = P / HW;
  const int p = P - n * HW;
  const int y = p / 56;
  const int xx = p - y * 56;

  const float* s2p = ws + WS_S2;
  const float* b2p = ws + WS_B2;
  const float* wyp = ws + WS_WY;
  const float* wxp = ws + WS_WX;
  const int* ayp = (const int*)ws + WS_AY;
  const int* axp = (const int*)ws + WS_AX;

  float acc[32];
#pragma unroll
  for (int o = 0; o < 32; ++o) acc[o] = 0.f;

  const float* fb = fmap + (n * CC + g * 32) * HW;

  for (int ci = 0; ci < 32; ++ci) {
    const int c = g * 32 + ci;
    const int y0 = y + ayp[c];
    const int x0 = xx + axp[c];
    const float wy = wyp[c], wx = wxp[c];
    const float s = s2p[c], b = b2p[c];
    const float* fc = fb + ci * HW;

    const bool yv0 = (unsigned)y0 < 56u;
    const bool yv1 = (unsigned)(y0 + 1) < 56u;
    const bool xv0 = (unsigned)x0 < 56u;
    const bool xv1 = (unsigned)(x0 + 1) < 56u;

    float g00 = (yv0 && xv0) ? fmaxf(fmaf(fc[y0 * 56 + x0], s, b), 0.f) : 0.f;
    float g01 = (yv0 && xv1) ? fmaxf(fmaf(fc[y0 * 56 + x0 + 1], s, b), 0.f) : 0.f;
    float g10 = (yv1 && xv0) ? fmaxf(fmaf(fc[(y0 + 1) * 56 + x0], s, b), 0.f) : 0.f;
    float g11 = (yv1 && xv1) ? fmaxf(fmaf(fc[(y0 + 1) * 56 + x0 + 1], s, b), 0.f) : 0.f;

    float h = (1.f - wy) * ((1.f - wx) * g00 + wx * g01) +
              wy * ((1.f - wx) * g10 + wx * g11);

    const float* wr = ws + WS_W2T + c * 32;
#pragma unroll
    for (int o = 0; o < 32; ++o) acc[o] = fmaf(wr[o], h, acc[o]);
  }

  const int ob = (n * CC + g * 32) * HW + p;
#pragma unroll
  for (int o = 0; o < 32; ++o) out[ob + o * HW] = acc[o] + x[ob + o * HW];
}

extern "C" void kernel_launch(void* const* d_in, const int* in_sizes, int n_in,
                              void* d_out, int out_size, void* d_ws, size_t ws_size,
                              hipStream_t stream) {
  const float* x     = (const float*)d_in[0];
  const float* prev  = (const float*)d_in[1];
  const float* g1    = (const float*)d_in[2];
  const float* be1   = (const float*)d_in[3];
  const float* m1    = (const float*)d_in[4];
  const float* v1    = (const float*)d_in[5];
  const float* g2    = (const float*)d_in[6];
  const float* be2   = (const float*)d_in[7];
  const float* m2    = (const float*)d_in[8];
  const float* v2    = (const float*)d_in[9];
  const float* w1    = (const float*)d_in[10];
  const float* w2    = (const float*)d_in[11];
  const float* shift = (const float*)d_in[12];

  float* out  = (float*)d_out;
  float* fmap = out + (size_t)NB * CC * HW;  // second output, written directly
  float* ws   = (float*)d_ws;

  precompute_k<<<1, 256, 0, stream>>>(g1, be1, m1, v1, g2, be2, m2, v2,
                                      w1, w2, shift, ws);
  k1_conv1<<<784, 256, 0, stream>>>(x, prev, ws, fmap);
  k2_shift_conv2<<<1568, 192, 0, stream>>>(x, fmap, ws, out);
}